// Round 1
// baseline (200.630 us; speedup 1.0000x reference)
//
#include <hip/hip_runtime.h>
#include <hip/hip_bf16.h>

#define NATOMS 50000
#define NEDGES 100000
#define AD 64
#define BD 16
#define PITCH 1096           // LDS row pitch in bf16 elems (1088 + 8)
#define MTILE 256
#define NTILES ((NEDGES + MTILE - 1) / MTILE)

typedef __bf16 bf16x8 __attribute__((ext_vector_type(8)));
typedef __bf16 bf16x4 __attribute__((ext_vector_type(4)));
typedef float  f32x16 __attribute__((ext_vector_type(16)));

__global__ __launch_bounds__(512, 1)
void edgenet_kernel(const float* __restrict__ atom,   // 50000 x 64
                    const float* __restrict__ bond,   // 100000 x 16
                    const int*   __restrict__ pair,   // 100000 x 2 (tgt, nbr)
                    const float* __restrict__ kern,   // 16 x 4096
                    const float* __restrict__ bias,   // 4096
                    float* __restrict__ out)          // 50000 x 64 (pre-zeroed)
{
    __shared__ __bf16 Blds[64 * PITCH];   // B[i][k], k in [0,1088)

    const int tid = threadIdx.x;

    // ---- stage B = [kernel | bias] into LDS as bf16 ----
    for (int q = tid; q < (16 * 4096) / 4; q += 512) {
        const int idx = q * 4;                  // flat index into kernel
        const int b = idx >> 12;                // 0..15
        const int i = (idx >> 6) & 63;          // output col
        const int j = idx & 63;                 // nbr dim
        const float4 v = *reinterpret_cast<const float4*>(kern + idx);
        bf16x4 w;
        w[0] = (__bf16)v.x; w[1] = (__bf16)v.y; w[2] = (__bf16)v.z; w[3] = (__bf16)v.w;
        *reinterpret_cast<bf16x4*>(Blds + i * PITCH + (b << 6) + j) = w;
    }
    for (int q = tid; q < 4096 / 4; q += 512) {
        const int idx = q * 4;
        const int i = idx >> 6;
        const int j = idx & 63;
        const float4 v = *reinterpret_cast<const float4*>(bias + idx);
        bf16x4 w;
        w[0] = (__bf16)v.x; w[1] = (__bf16)v.y; w[2] = (__bf16)v.z; w[3] = (__bf16)v.w;
        *reinterpret_cast<bf16x4*>(Blds + i * PITCH + 1024 + j) = w;
    }
    __syncthreads();

    const int wave = tid >> 6;
    const int lane = tid & 63;
    const int l31  = lane & 31;
    const int half = lane >> 5;     // k-half for A/B fragments
    const int h8   = half * 8;

    const __bf16* __restrict__ Brow0 = Blds + l31 * PITCH;         // cols 0..31
    const __bf16* __restrict__ Brow1 = Blds + (32 + l31) * PITCH;  // cols 32..63

    for (int tile = blockIdx.x; tile < NTILES; tile += gridDim.x) {
        const int eb = tile * MTILE + wave * 32;
        // A-side row for this lane
        const int eA = eb + l31;
        const float scale = (eA < NEDGES) ? 1.0f : 0.0f;
        const int eAc = (eA < NEDGES) ? eA : 0;

        int ni = pair[2 * eAc + 1];
        if ((unsigned)ni >= NATOMS) ni = 0;   // safety: bad dtype/garbage guard
        const float* nbrRow  = atom + (long)ni * AD;
        const float* bondRow = bond + (long)eAc * BD;

        // preload the half-row of nbr this lane ever needs: j = 16q + 8*half + r
        float nb[4][8];
        #pragma unroll
        for (int q = 0; q < 4; ++q) {
            const float4 lo = *reinterpret_cast<const float4*>(nbrRow + q * 16 + h8);
            const float4 hi = *reinterpret_cast<const float4*>(nbrRow + q * 16 + h8 + 4);
            nb[q][0] = lo.x * scale; nb[q][1] = lo.y * scale;
            nb[q][2] = lo.z * scale; nb[q][3] = lo.w * scale;
            nb[q][4] = hi.x * scale; nb[q][5] = hi.y * scale;
            nb[q][6] = hi.z * scale; nb[q][7] = hi.w * scale;
        }
        float bd[16];
        #pragma unroll
        for (int q = 0; q < 4; ++q) {
            const float4 v = *reinterpret_cast<const float4*>(bondRow + q * 4);
            bd[q * 4 + 0] = v.x; bd[q * 4 + 1] = v.y;
            bd[q * 4 + 2] = v.z; bd[q * 4 + 3] = v.w;
        }

        f32x16 acc0, acc1;
        #pragma unroll
        for (int r = 0; r < 16; ++r) { acc0[r] = 0.f; acc1[r] = 0.f; }

        // main K: k = 16t + 8*half + r ;  b = t>>2 ; j = 16*(t&3) + 8*half + r
        #pragma unroll
        for (int t = 0; t < 64; ++t) {
            const float bv = bd[t >> 2];
            bf16x8 a;
            #pragma unroll
            for (int r = 0; r < 8; ++r) a[r] = (__bf16)(bv * nb[t & 3][r]);
            const int k0 = t * 16 + h8;
            const bf16x8 b0 = *reinterpret_cast<const bf16x8*>(Brow0 + k0);
            const bf16x8 b1 = *reinterpret_cast<const bf16x8*>(Brow1 + k0);
            acc0 = __builtin_amdgcn_mfma_f32_32x32x16_bf16(a, b0, acc0, 0, 0, 0);
            acc1 = __builtin_amdgcn_mfma_f32_32x32x16_bf16(a, b1, acc1, 0, 0, 0);
        }
        // bias rows: k = 1024 + 16*(t-64) + 8*half + r ; A = nbr (scaled)
        #pragma unroll
        for (int t = 64; t < 68; ++t) {
            bf16x8 a;
            #pragma unroll
            for (int r = 0; r < 8; ++r) a[r] = (__bf16)(nb[t - 64][r]);
            const int k0 = t * 16 + h8;
            const bf16x8 b0 = *reinterpret_cast<const bf16x8*>(Brow0 + k0);
            const bf16x8 b1 = *reinterpret_cast<const bf16x8*>(Brow1 + k0);
            acc0 = __builtin_amdgcn_mfma_f32_32x32x16_bf16(a, b0, acc0, 0, 0, 0);
            acc1 = __builtin_amdgcn_mfma_f32_32x32x16_bf16(a, b1, acc1, 0, 0, 0);
        }

        // ---- scatter: D row = (r&3) + 8*(r>>2) + 4*half ; col = nf*32 + l31
        const int rb = eb + 4 * half;
        #pragma unroll
        for (int r = 0; r < 16; ++r) {
            const int e = rb + (r & 3) + 8 * (r >> 2);
            if (e < NEDGES) {
                int tg = pair[2 * e];
                if ((unsigned)tg < NATOMS) {
                    float* o = out + (long)tg * AD;
                    atomicAdd(o + l31,      acc0[r]);
                    atomicAdd(o + 32 + l31, acc1[r]);
                }
            }
        }
    }
}

extern "C" void kernel_launch(void* const* d_in, const int* in_sizes, int n_in,
                              void* d_out, int out_size, void* d_ws, size_t ws_size,
                              hipStream_t stream) {
    const float* atom = (const float*)d_in[0];
    const float* bond = (const float*)d_in[1];
    const int*   pair = (const int*)d_in[2];
    const float* kern = (const float*)d_in[3];
    const float* bias = (const float*)d_in[4];
    float* out = (float*)d_out;

    hipMemsetAsync(d_out, 0, (size_t)out_size * sizeof(float), stream);

    const int grid = NTILES < 256 ? NTILES : 256;
    edgenet_kernel<<<grid, 512, 0, stream>>>(atom, bond, pair, kern, bias, out);
}